// Round 1
// baseline (763.995 us; speedup 1.0000x reference)
//
#include <hip/hip_runtime.h>

#define NN 100000
#define NE 625000
#define HD 128

typedef unsigned int u32;
typedef unsigned short u16;
typedef __bf16 bf16x8 __attribute__((ext_vector_type(8)));
typedef float f32x4 __attribute__((ext_vector_type(4)));

__device__ __forceinline__ u16 f2b(float f) {
  u32 u = __float_as_uint(f);
  u32 r = (u + 0x7FFFu + ((u >> 16) & 1u)) >> 16;
  return (u16)r;
}
__device__ __forceinline__ float b2f(u32 u) { return __uint_as_float(u << 16); }

// ---- weight transpose+cast: Wt[l][which][h][d] = W[l][d][h] as bf16 ----
__global__ void k_prep_w(const float* __restrict__ Wl, const float* __restrict__ Wr,
                         const float* __restrict__ Wlin, u16* __restrict__ Wt) {
  int i = blockIdx.x * blockDim.x + threadIdx.x;
  if (i >= 6 * 16384) return;
  int mat = i >> 14;           // 0..5
  int l = mat / 3, which = mat % 3;
  int rem = i & 16383;
  int hh = rem >> 7, dd = rem & 127;
  const float* src = (which == 0) ? Wl : (which == 1) ? Wr : Wlin;
  float v = src[l * 16384 + dd * 128 + hh];
  Wt[l * (3 * 16384) + which * 16384 + hh * 128 + dd] = f2b(v);
}

// ---- cast x fp32 -> bf16 ----
__global__ void k_cast_x(const float* __restrict__ x, u16* __restrict__ xb) {
  int i = blockIdx.x * blockDim.x + threadIdx.x;
  if (i >= NN * 32) return;
  float4 v = *(const float4*)(x + i * 4);
  uint2 o;
  o.x = (u32)f2b(v.x) | ((u32)f2b(v.y) << 16);
  o.y = (u32)f2b(v.z) | ((u32)f2b(v.w) << 16);
  *(uint2*)(xb + i * 4) = o;
}

// ---- CSR build ----
__global__ void k_hist(const int* __restrict__ dst, int* __restrict__ deg) {
  int e = blockIdx.x * blockDim.x + threadIdx.x;
  if (e < NE) atomicAdd(&deg[dst[e]], 1);
}

__global__ void k_alloc(const int* __restrict__ deg, int* __restrict__ row_start,
                        int* __restrict__ cursor) {
  int idx = blockIdx.x * blockDim.x + threadIdx.x;
  int lane = threadIdx.x & 63;
  int v = (idx < NN) ? deg[idx] : 0;
  int incl = v;
  #pragma unroll
  for (int off = 1; off < 64; off <<= 1) {
    int t = __shfl_up(incl, off, 64);
    if (lane >= off) incl += t;
  }
  int total = __shfl(incl, 63, 64);
  int base = 0;
  if (lane == 63) base = atomicAdd(cursor, total);
  base = __shfl(base, 63, 64);
  if (idx < NN) row_start[idx] = base + incl - v;
}

__global__ void k_fill(const int* __restrict__ src, const int* __restrict__ dst,
                       const int* __restrict__ row_start, int* __restrict__ cnt,
                       int* __restrict__ ss) {
  int e = blockIdx.x * blockDim.x + threadIdx.x;
  if (e >= NE) return;
  int d = dst[e];
  int p = row_start[d] + atomicAdd(&cnt[d], 1);
  ss[p] = src[e];
}

// ---- generic [NN,128]x[128,128] bf16 MFMA GEMM, fragment-major LDS ----
// mode 0: o16[g][c] = bf16(acc + bias[c])
// mode 1: o32[g][c] = acc + bias[c] + b2f(res[g][c])
__global__ __launch_bounds__(256) void k_gemm(
    const u16* __restrict__ A, const u16* __restrict__ Bt,
    const float* __restrict__ bias, u16* __restrict__ o16,
    const u16* __restrict__ res, float* __restrict__ o32, int mode) {
  __shared__ __align__(16) u16 lA[64 * 128];
  __shared__ __align__(16) u16 lB[128 * 128];
  const int tid = threadIdx.x;
  const int m0 = blockIdx.x * 64;
  const int rr = tid >> 4;
  const int seg = tid & 15;
  const int sK = seg >> 2;
  const int qd = seg & 3;
  #pragma unroll
  for (int p = 0; p < 4; ++p) {
    int row = p * 16 + rr;
    int g = m0 + row;
    uint4 v = make_uint4(0u, 0u, 0u, 0u);
    if (g < NN) v = *(const uint4*)(A + g * HD + seg * 8);
    *(uint4*)(lA + (((row >> 4) * 4 + sK) * 64 + qd * 16 + (row & 15)) * 8) = v;
  }
  #pragma unroll
  for (int p = 0; p < 8; ++p) {
    int n = p * 16 + rr;
    uint4 v = *(const uint4*)(Bt + n * HD + seg * 8);
    *(uint4*)(lB + (((n >> 4) * 4 + sK) * 64 + qd * 16 + (n & 15)) * 8) = v;
  }
  __syncthreads();
  const int w = tid >> 6;
  const int lane = tid & 63;
  bf16x8 af[4];
  #pragma unroll
  for (int s = 0; s < 4; ++s)
    af[s] = *(const bf16x8*)(lA + ((w * 4 + s) * 64 + lane) * 8);
  const int colt = lane & 15;
  const int rq = (lane >> 4) * 4;
  #pragma unroll
  for (int t = 0; t < 8; ++t) {
    f32x4 acc = {0.f, 0.f, 0.f, 0.f};
    #pragma unroll
    for (int s = 0; s < 4; ++s) {
      bf16x8 bf = *(const bf16x8*)(lB + ((t * 4 + s) * 64 + lane) * 8);
      acc = __builtin_amdgcn_mfma_f32_16x16x32_bf16(af[s], bf, acc, 0, 0, 0);
    }
    const int c = t * 16 + colt;
    const float bs = bias[c];
    #pragma unroll
    for (int r = 0; r < 4; ++r) {
      int g = m0 + w * 16 + rq + r;
      if (g < NN) {
        if (mode == 0)
          o16[g * HD + c] = f2b(acc[r] + bs);
        else
          o32[g * HD + c] = acc[r] + bs + b2f((u32)res[g * HD + c]);
      }
    }
  }
}

// ---- fused edge phase: one wave per dst; softmax w/o max-subtraction ----
__global__ __launch_bounds__(256) void k_edge(
    const u16* __restrict__ xs_b, const u16* __restrict__ xd_b,
    const int* __restrict__ row_start, const int* __restrict__ deg,
    const int* __restrict__ ss, const float* __restrict__ att,
    const float* __restrict__ cb, u16* __restrict__ out_b) {
  int dv = blockIdx.x * 4 + (threadIdx.x >> 6);
  if (dv >= NN) return;
  int lane = threadIdx.x & 63;
  float a0 = att[2 * lane], a1 = att[2 * lane + 1];
  u32 xdp = ((const u32*)xd_b)[dv * 64 + lane];
  float xd0 = b2f(xdp & 0xFFFFu), xd1 = b2f(xdp >> 16);
  int base = row_start[dv], n = deg[dv];
  float acc0 = 0.f, acc1 = 0.f, wsum = 0.f;
  for (int e = 0; e < n; ++e) {
    int s = ss[base + e];
    u32 xp = ((const u32*)xs_b)[s * 64 + lane];
    float x0 = b2f(xp & 0xFFFFu), x1 = b2f(xp >> 16);
    float t0 = x0 + xd0; t0 = (t0 > 0.f) ? t0 : 0.2f * t0;
    float t1 = x1 + xd1; t1 = (t1 > 0.f) ? t1 : 0.2f * t1;
    float p = a0 * t0 + a1 * t1;
    #pragma unroll
    for (int off = 32; off > 0; off >>= 1) p += __shfl_xor(p, off, 64);
    float wg = __expf(p);
    wsum += wg; acc0 += wg * x0; acc1 += wg * x1;
  }
  float inv = 1.f / (wsum + 1e-16f);
  float o0 = acc0 * inv + cb[2 * lane];
  float o1 = acc1 * inv + cb[2 * lane + 1];
  ((u32*)out_b)[dv * 64 + lane] = (u32)f2b(o0) | ((u32)f2b(o1) << 16);
}

// ---- BN stats: per-channel sum/sumsq ----
__global__ __launch_bounds__(256) void k_stats(const float* __restrict__ h,
                                               float* __restrict__ ssum,
                                               float* __restrict__ ssq) {
  int c = threadIdx.x & 127;
  int half = threadIdx.x >> 7;
  int r0 = blockIdx.x * 512 + half;
  float s = 0.f, q = 0.f;
  for (int i = 0; i < 256; ++i) {
    int r = r0 + i * 2;
    if (r < NN) { float v = h[r * 128 + c]; s += v; q += v * v; }
  }
  __shared__ float ls[256], lq[256];
  ls[threadIdx.x] = s; lq[threadIdx.x] = q;
  __syncthreads();
  if (threadIdx.x < 128) {
    atomicAdd(&ssum[c], ls[threadIdx.x] + ls[threadIdx.x + 128]);
    atomicAdd(&ssq[c], lq[threadIdx.x] + lq[threadIdx.x + 128]);
  }
}

// ---- BN apply (+relu, + bf16 cast for next layer OR fp32 final out) ----
__global__ void k_bn(const float* __restrict__ h, const float* __restrict__ ssum,
                     const float* __restrict__ ssq, const float* __restrict__ gamma,
                     const float* __restrict__ beta, u16* __restrict__ xb_out,
                     float* __restrict__ fout, int relu) {
  int i = blockIdx.x * blockDim.x + threadIdx.x;
  if (i >= NN * 64) return;
  int row = i >> 6, cp = (i & 63) * 2;
  float2 v = *(const float2*)(h + row * 128 + cp);
  const float invn = 1.0f / 100000.0f;
  float mu0 = ssum[cp] * invn, mu1 = ssum[cp + 1] * invn;
  float va0 = fmaxf(ssq[cp] * invn - mu0 * mu0, 0.f);
  float va1 = fmaxf(ssq[cp + 1] * invn - mu1 * mu1, 0.f);
  float s0 = rsqrtf(va0 + 1e-5f) * gamma[cp];
  float s1 = rsqrtf(va1 + 1e-5f) * gamma[cp + 1];
  float o0 = (v.x - mu0) * s0 + beta[cp];
  float o1 = (v.y - mu1) * s1 + beta[cp + 1];
  if (relu) { o0 = fmaxf(o0, 0.f); o1 = fmaxf(o1, 0.f); }
  if (xb_out) ((u32*)xb_out)[i] = (u32)f2b(o0) | ((u32)f2b(o1) << 16);
  else *(float2*)(fout + row * 128 + cp) = make_float2(o0, o1);
}

extern "C" void kernel_launch(void* const* d_in, const int* in_sizes, int n_in,
                              void* d_out, int out_size, void* d_ws, size_t ws_size,
                              hipStream_t stream) {
  const float* x    = (const float*)d_in[0];
  const int*   ei   = (const int*)d_in[1];
  const float* Wl   = (const float*)d_in[2];
  const float* bl   = (const float*)d_in[3];
  const float* Wr   = (const float*)d_in[4];
  const float* br   = (const float*)d_in[5];
  const float* att  = (const float*)d_in[6];
  const float* cb   = (const float*)d_in[7];
  const float* Wlin = (const float*)d_in[8];
  const float* blin = (const float*)d_in[9];
  const float* gm   = (const float*)d_in[10];
  const float* bt   = (const float*)d_in[11];
  const int* esrc = ei;
  const int* edst = ei + NE;
  float* h = (float*)d_out;  // d_out doubles as fp32 h scratch

  // ws layout (all 16B-aligned by construction)
  u16* xb    = (u16*)d_ws;            // N*128 bf16
  u16* xs_b  = xb + NN * HD;
  u16* xd_b  = xs_b + NN * HD;
  u16* out_b = xd_b + NN * HD;
  u16* Wt    = out_b + NN * HD;       // 6*16384 bf16
  int* deg       = (int*)(Wt + 6 * 16384);
  int* cnt       = deg + NN;
  int* cursor    = cnt + NN;
  int* row_start = cursor + 1;
  int* srcs      = row_start + NN;    // E ints
  float* ssum    = (float*)(srcs + NE);
  float* ssq     = ssum + 128;

  hipMemsetAsync(deg, 0, (size_t)(2 * NN + 1) * 4, stream);
  k_prep_w<<<(6 * 16384 + 255) / 256, 256, 0, stream>>>(Wl, Wr, Wlin, Wt);
  k_cast_x<<<(NN * 32 + 255) / 256, 256, 0, stream>>>(x, xb);
  k_hist<<<(NE + 255) / 256, 256, 0, stream>>>(edst, deg);
  k_alloc<<<(NN + 255) / 256, 256, 0, stream>>>(deg, row_start, cursor);
  k_fill<<<(NE + 255) / 256, 256, 0, stream>>>(esrc, edst, row_start, cnt, srcs);

  const int gemm_grid = (NN + 63) / 64;
  for (int l = 0; l < 2; ++l) {
    const u16* wt_l   = Wt + l * 3 * 16384;
    const u16* wt_r   = wt_l + 16384;
    const u16* wt_lin = wt_l + 2 * 16384;
    k_gemm<<<gemm_grid, 256, 0, stream>>>(xb, wt_l, bl + l * 128, xs_b, nullptr, nullptr, 0);
    k_gemm<<<gemm_grid, 256, 0, stream>>>(xb, wt_r, br + l * 128, xd_b, nullptr, nullptr, 0);
    k_edge<<<(NN + 3) / 4, 256, 0, stream>>>(xs_b, xd_b, row_start, deg, srcs,
                                             att + l * 128, cb + l * 128, out_b);
    k_gemm<<<gemm_grid, 256, 0, stream>>>(out_b, wt_lin, blin + l * 128, nullptr, out_b, h, 1);
    hipMemsetAsync(ssum, 0, 256 * 4, stream);
    k_stats<<<(NN + 511) / 512, 256, 0, stream>>>(h, ssum, ssq);
    k_bn<<<(NN * 64 + 255) / 256, 256, 0, stream>>>(
        h, ssum, ssq, gm + l * 128, bt + l * 128,
        (l == 0) ? xb : nullptr, (l == 0) ? nullptr : h, (l == 0) ? 1 : 0);
  }
}